// Round 1
// baseline (418.115 us; speedup 1.0000x reference)
//
#include <hip/hip_runtime.h>
#include <hip/hip_bf16.h>

// MoE: N=8192 tokens, D=1024, E=8 experts, top-2 routing.
// Inputs (fp32): x[8192,1024], Wr[1024,8], br[8], W[8,1024,1024], b[8,1024]
// Output (fp32): out[8192,1024]
//
// Strategy: fp32 routing (exact top-k), bf16 MFMA routed expert GEMM
// (34.4 GFLOP useful vs 137 dense), fused gated atomic scatter-combine.

#define NTOK 8192
#define DM   1024
#define NEXP 8
#define CAP  8192   // per-expert slot capacity (worst case)

typedef __attribute__((ext_vector_type(8))) short bf16x8;
typedef __attribute__((ext_vector_type(4))) float f32x4;

__device__ __forceinline__ unsigned short f2bf(float f) {
  unsigned u = __float_as_uint(f);
  unsigned r = (u + 0x7fffu + ((u >> 16) & 1u)) >> 16;
  return (unsigned short)r;
}

__device__ __forceinline__ void gl_lds16(const void* g, void* l) {
  __builtin_amdgcn_global_load_lds(
      (const __attribute__((address_space(1))) unsigned int*)g,
      (__attribute__((address_space(3))) unsigned int*)l, 16, 0, 0);
}

// ---------------- W transpose + bf16 cast: Wt[e][h][d] = bf16(W[e][d][h]) ---
__global__ __launch_bounds__(256) void transpose_w_kernel(
    const float* __restrict__ W, unsigned short* __restrict__ Wt) {
  __shared__ float tile[64][65];  // +1 pad: conflict-free transpose
  const int e = blockIdx.z;
  const int d0 = blockIdx.y * 64, h0 = blockIdx.x * 64;
  const float* Ws = W + (size_t)e * DM * DM;
  unsigned short* Wd = Wt + (size_t)e * DM * DM;
  const int r = threadIdx.x >> 4;          // 0..15
  const int c4 = (threadIdx.x & 15) * 4;   // 0..60
#pragma unroll
  for (int k = 0; k < 4; k++) {
    int row = r + k * 16;
    float4 v = *(const float4*)(Ws + (size_t)(d0 + row) * DM + h0 + c4);
    tile[row][c4 + 0] = v.x; tile[row][c4 + 1] = v.y;
    tile[row][c4 + 2] = v.z; tile[row][c4 + 3] = v.w;
  }
  __syncthreads();
#pragma unroll
  for (int k = 0; k < 4; k++) {
    int hrow = r + k * 16;
    ushort4 o;
    o.x = f2bf(tile[c4 + 0][hrow]);
    o.y = f2bf(tile[c4 + 1][hrow]);
    o.z = f2bf(tile[c4 + 2][hrow]);
    o.w = f2bf(tile[c4 + 3][hrow]);
    *(ushort4*)(Wd + (size_t)(h0 + hrow) * DM + d0 + c4) = o;
  }
}

// ---------------- Router: fp32 logits, top-2, gates, slot assignment --------
// One wave per token. Lane l covers columns [l*16, l*16+16). Also casts x->bf16.
__global__ __launch_bounds__(256) void router_kernel(
    const float* __restrict__ x, const float* __restrict__ Wr,
    const float* __restrict__ br, unsigned short* __restrict__ xbf,
    int* __restrict__ counts, int* __restrict__ tok, float* __restrict__ gat) {
  const int tid = threadIdx.x;
  const int wave = tid >> 6, lane = tid & 63;
  const int t = blockIdx.x * 4 + wave;
  const int c0 = lane * 16;
  const float* xr = x + (size_t)t * DM + c0;

  float v[16];
#pragma unroll
  for (int i = 0; i < 4; i++) {
    float4 f = *(const float4*)(xr + i * 4);
    v[i * 4 + 0] = f.x; v[i * 4 + 1] = f.y; v[i * 4 + 2] = f.z; v[i * 4 + 3] = f.w;
  }
  // bf16 cast of x (packed 16B stores)
  union { unsigned short s[8]; uint4 q; } pk;
#pragma unroll
  for (int half = 0; half < 2; half++) {
#pragma unroll
    for (int i = 0; i < 8; i++) pk.s[i] = f2bf(v[half * 8 + i]);
    *(uint4*)(xbf + (size_t)t * DM + c0 + half * 8) = pk.q;
  }
  // partial logits: p[e] += x[c] * Wr[c][e]
  float p[8] = {0, 0, 0, 0, 0, 0, 0, 0};
  const float* wr = Wr + (size_t)c0 * NEXP;
#pragma unroll
  for (int i = 0; i < 16; i++) {
    float xv = v[i];
    float4 wl = *(const float4*)(wr + i * 8);
    float4 wh = *(const float4*)(wr + i * 8 + 4);
    p[0] += xv * wl.x; p[1] += xv * wl.y; p[2] += xv * wl.z; p[3] += xv * wl.w;
    p[4] += xv * wh.x; p[5] += xv * wh.y; p[6] += xv * wh.z; p[7] += xv * wh.w;
  }
#pragma unroll
  for (int off = 32; off >= 1; off >>= 1) {
#pragma unroll
    for (int e = 0; e < 8; e++) p[e] += __shfl_xor(p[e], off, 64);
  }
  if (lane == 0) {
    float lg[8];
#pragma unroll
    for (int e = 0; e < 8; e++) lg[e] = p[e] + br[e];
    // top-2, first-occurrence tie-break (matches jax.lax.top_k)
    float v0 = lg[0]; int i0 = 0;
#pragma unroll
    for (int e = 1; e < 8; e++) if (lg[e] > v0) { v0 = lg[e]; i0 = e; }
    float v1 = -3.4e38f; int i1 = 0;
#pragma unroll
    for (int e = 0; e < 8; e++)
      if (e != i0 && lg[e] > v1) { v1 = lg[e]; i1 = e; }
    float ee = __expf(v1 - v0);
    float g0 = 1.0f / (1.0f + ee);
    float g1 = ee / (1.0f + ee);
    int s0 = atomicAdd(&counts[i0], 1);
    tok[i0 * CAP + s0] = t; gat[i0 * CAP + s0] = g0;
    int s1 = atomicAdd(&counts[i1], 1);
    tok[i1 * CAP + s1] = t; gat[i1 * CAP + s1] = g1;
  }
}

// ---------------- Routed expert GEMM + gated atomic combine -----------------
// Tile 128x128, BK=32, mfma_f32_16x16x32_bf16. 4 waves in 2x2, each 64x64.
// A rows gathered by token id (per-lane gptr into global_load_lds).
// LDS layout [row][32] bf16 (64B rows), chunk-XOR swizzle -> 2-way (free).
__global__ __launch_bounds__(256) void moe_gemm_kernel(
    const unsigned short* __restrict__ xbf, const unsigned short* __restrict__ wt,
    const float* __restrict__ bias, const int* __restrict__ counts,
    const int* __restrict__ tok, const float* __restrict__ gat,
    float* __restrict__ out) {
  const int e = blockIdx.z;
  const int cnt = counts[e];
  const int m0 = blockIdx.y * 128;
  if (m0 >= cnt) return;  // covers cnt==0
  const int n0 = blockIdx.x * 128;

  __shared__ __align__(16) unsigned short sA[128 * 32];
  __shared__ __align__(16) unsigned short sB[128 * 32];
  __shared__ int sTok[128];
  __shared__ float sGate[128];

  const int tid = threadIdx.x, wave = tid >> 6, lane = tid & 63;

  if (tid < 128) {
    int sr = m0 + tid;
    int cl = (sr < cnt) ? sr : (cnt - 1);
    sTok[tid] = tok[e * CAP + cl];
    sGate[tid] = gat[e * CAP + cl];
  }
  __syncthreads();

  // staging assignment: wave w stages 16-row groups {w, w+4} of A and B.
  // lane i -> row g*16 + (i>>2), chunk slot i&3; source chunk XOR-swizzled.
  const int rA1 = wave * 16 + (lane >> 2);
  const int rA2 = rA1 + 64;
  const int cch = lane & 3;
  const int cg1 = (cch ^ ((rA1 >> 1) & 3)) * 8;  // elements
  const int cg2 = (cch ^ ((rA2 >> 1) & 3)) * 8;
  const unsigned short* pA1 = xbf + (size_t)sTok[rA1] * DM + cg1;
  const unsigned short* pA2 = xbf + (size_t)sTok[rA2] * DM + cg2;
  const unsigned short* wte = wt + (size_t)e * DM * DM;
  const unsigned short* pB1 = wte + (size_t)(n0 + rA1) * DM + cg1;
  const unsigned short* pB2 = wte + (size_t)(n0 + rA2) * DM + cg2;
  unsigned short* lA1 = sA + wave * 512;        // 1024B per 16-row group
  unsigned short* lA2 = sA + (wave + 4) * 512;
  unsigned short* lB1 = sB + wave * 512;
  unsigned short* lB2 = sB + (wave + 4) * 512;

  // fragment read offsets (shorts): row*32 + swizzled 8-elem chunk
  const int q = lane >> 4, ml = lane & 15;
  const int wm = (wave >> 1) * 64, wn = (wave & 1) * 64;
  int offA[4], offB[4];
#pragma unroll
  for (int i = 0; i < 4; i++) {
    int row = wm + i * 16 + ml;
    offA[i] = row * 32 + (q ^ ((row >> 1) & 3)) * 8;
    int rowb = wn + i * 16 + ml;
    offB[i] = rowb * 32 + (q ^ ((rowb >> 1) & 3)) * 8;
  }

  f32x4 acc[4][4] = {};

  for (int k0 = 0; k0 < DM; k0 += 32) {
    gl_lds16(pA1 + k0, lA1);
    gl_lds16(pA2 + k0, lA2);
    gl_lds16(pB1 + k0, lB1);
    gl_lds16(pB2 + k0, lB2);
    __syncthreads();
    bf16x8 af[4], bf[4];
#pragma unroll
    for (int i = 0; i < 4; i++) af[i] = *(const bf16x8*)(sA + offA[i]);
#pragma unroll
    for (int i = 0; i < 4; i++) bf[i] = *(const bf16x8*)(sB + offB[i]);
#pragma unroll
    for (int mt = 0; mt < 4; mt++)
#pragma unroll
      for (int nt = 0; nt < 4; nt++)
        acc[mt][nt] = __builtin_amdgcn_mfma_f32_16x16x32_bf16(
            af[mt], bf[nt], acc[mt][nt], 0, 0, 0);
    __syncthreads();
  }

  // epilogue: out[t][col] += g * (acc + bias[e][col])  (exactly 2 adds/elem)
  const float* be = bias + (size_t)e * DM;
#pragma unroll
  for (int mt = 0; mt < 4; mt++) {
    int rbase = wm + mt * 16 + q * 4;
#pragma unroll
    for (int r = 0; r < 4; r++) {
      int row = rbase + r;
      if (m0 + row >= cnt) continue;
      int t = sTok[row];
      float g = sGate[row];
      float* orow = out + (size_t)t * DM + n0;
#pragma unroll
      for (int nt = 0; nt < 4; nt++) {
        int col = wn + nt * 16 + ml;
        atomicAdd(orow + col, g * (acc[mt][nt][r] + be[n0 + col]));
      }
    }
  }
}

extern "C" void kernel_launch(void* const* d_in, const int* in_sizes, int n_in,
                              void* d_out, int out_size, void* d_ws, size_t ws_size,
                              hipStream_t stream) {
  const float* x  = (const float*)d_in[0];
  const float* Wr = (const float*)d_in[1];
  const float* br = (const float*)d_in[2];
  const float* W  = (const float*)d_in[3];
  const float* b  = (const float*)d_in[4];
  float* out = (float*)d_out;

  // workspace layout (~33.6 MB)
  char* ws = (char*)d_ws;
  unsigned short* xbf = (unsigned short*)ws;                        // 16 MB
  unsigned short* wt  = (unsigned short*)(ws + (16u << 20));        // 16 MB
  int*   counts = (int*)(ws + (32u << 20));                         // 32 B
  int*   tok    = (int*)(ws + (32u << 20) + 4096);                  // 256 KB
  float* gat    = (float*)(ws + (32u << 20) + 4096 + (256u << 10)); // 256 KB

  hipMemsetAsync(d_out, 0, (size_t)out_size * sizeof(float), stream);
  hipMemsetAsync(counts, 0, NEXP * sizeof(int), stream);

  transpose_w_kernel<<<dim3(16, 16, 8), 256, 0, stream>>>(W, wt);
  router_kernel<<<NTOK / 4, 256, 0, stream>>>(x, Wr, br, xbf, counts, tok, gat);
  moe_gemm_kernel<<<dim3(8, 64, 8), 256, 0, stream>>>(xbf, wt, b, counts, tok,
                                                      gat, out);
}

// Round 2
// 264.420 us; speedup vs baseline: 1.5813x; 1.5813x over previous
//
#include <hip/hip_runtime.h>
#include <hip/hip_bf16.h>

// MoE: N=8192 tokens, D=1024, E=8 experts, top-2 routing.
// Inputs (fp32): x[8192,1024], Wr[1024,8], br[8], W[8,1024,1024], b[8,1024]
// Output (fp32): out[8192,1024]
//
// R1 fix: router had 16384 serialized atomics on one cache line (202 us).
// Now: atomic-free router_compute -> per-token topk record, then a
// block-aggregated scatter (128 global atomics total).

#define NTOK 8192
#define DM   1024
#define NEXP 8
#define CAP  8192   // per-expert slot capacity (worst case)

typedef __attribute__((ext_vector_type(8))) short bf16x8;
typedef __attribute__((ext_vector_type(4))) float f32x4;

__device__ __forceinline__ unsigned short f2bf(float f) {
  unsigned u = __float_as_uint(f);
  unsigned r = (u + 0x7fffu + ((u >> 16) & 1u)) >> 16;
  return (unsigned short)r;
}

__device__ __forceinline__ void gl_lds16(const void* g, void* l) {
  __builtin_amdgcn_global_load_lds(
      (const __attribute__((address_space(1))) unsigned int*)g,
      (__attribute__((address_space(3))) unsigned int*)l, 16, 0, 0);
}

// ---------------- W transpose + bf16 cast: Wt[e][h][d] = bf16(W[e][d][h]) ---
__global__ __launch_bounds__(256) void transpose_w_kernel(
    const float* __restrict__ W, unsigned short* __restrict__ Wt) {
  __shared__ float tile[64][65];  // +1 pad: conflict-free transpose
  const int e = blockIdx.z;
  const int d0 = blockIdx.y * 64, h0 = blockIdx.x * 64;
  const float* Ws = W + (size_t)e * DM * DM;
  unsigned short* Wd = Wt + (size_t)e * DM * DM;
  const int r = threadIdx.x >> 4;          // 0..15
  const int c4 = (threadIdx.x & 15) * 4;   // 0..60
#pragma unroll
  for (int k = 0; k < 4; k++) {
    int row = r + k * 16;
    float4 v = *(const float4*)(Ws + (size_t)(d0 + row) * DM + h0 + c4);
    tile[row][c4 + 0] = v.x; tile[row][c4 + 1] = v.y;
    tile[row][c4 + 2] = v.z; tile[row][c4 + 3] = v.w;
  }
  __syncthreads();
#pragma unroll
  for (int k = 0; k < 4; k++) {
    int hrow = r + k * 16;
    ushort4 o;
    o.x = f2bf(tile[c4 + 0][hrow]);
    o.y = f2bf(tile[c4 + 1][hrow]);
    o.z = f2bf(tile[c4 + 2][hrow]);
    o.w = f2bf(tile[c4 + 3][hrow]);
    *(ushort4*)(Wd + (size_t)(h0 + hrow) * DM + d0 + c4) = o;
  }
}

// ---------------- Router compute: fp32 logits, top-2, gates (atomic-free) ---
// One wave per token. Lane l covers columns [l*16, l*16+16). Also casts x->bf16.
// Writes topk[t] = {i0, i1, bits(g0), bits(g1)}.
__global__ __launch_bounds__(256) void router_compute_kernel(
    const float* __restrict__ x, const float* __restrict__ Wr,
    const float* __restrict__ br, unsigned short* __restrict__ xbf,
    int4* __restrict__ topk) {
  const int tid = threadIdx.x;
  const int wave = tid >> 6, lane = tid & 63;
  const int t = blockIdx.x * 4 + wave;
  const int c0 = lane * 16;
  const float* xr = x + (size_t)t * DM + c0;

  float v[16];
#pragma unroll
  for (int i = 0; i < 4; i++) {
    float4 f = *(const float4*)(xr + i * 4);
    v[i * 4 + 0] = f.x; v[i * 4 + 1] = f.y; v[i * 4 + 2] = f.z; v[i * 4 + 3] = f.w;
  }
  // bf16 cast of x (packed 16B stores)
  union { unsigned short s[8]; uint4 q; } pk;
#pragma unroll
  for (int half = 0; half < 2; half++) {
#pragma unroll
    for (int i = 0; i < 8; i++) pk.s[i] = f2bf(v[half * 8 + i]);
    *(uint4*)(xbf + (size_t)t * DM + c0 + half * 8) = pk.q;
  }
  // partial logits: p[e] += x[c] * Wr[c][e]
  float p[8] = {0, 0, 0, 0, 0, 0, 0, 0};
  const float* wr = Wr + (size_t)c0 * NEXP;
#pragma unroll
  for (int i = 0; i < 16; i++) {
    float xv = v[i];
    float4 wl = *(const float4*)(wr + i * 8);
    float4 wh = *(const float4*)(wr + i * 8 + 4);
    p[0] += xv * wl.x; p[1] += xv * wl.y; p[2] += xv * wl.z; p[3] += xv * wl.w;
    p[4] += xv * wh.x; p[5] += xv * wh.y; p[6] += xv * wh.z; p[7] += xv * wh.w;
  }
#pragma unroll
  for (int off = 32; off >= 1; off >>= 1) {
#pragma unroll
    for (int e = 0; e < 8; e++) p[e] += __shfl_xor(p[e], off, 64);
  }
  if (lane == 0) {
    float lg[8];
#pragma unroll
    for (int e = 0; e < 8; e++) lg[e] = p[e] + br[e];
    // top-2, first-occurrence tie-break (matches jax.lax.top_k)
    float v0 = lg[0]; int i0 = 0;
#pragma unroll
    for (int e = 1; e < 8; e++) if (lg[e] > v0) { v0 = lg[e]; i0 = e; }
    float v1 = -3.4e38f; int i1 = 0;
#pragma unroll
    for (int e = 0; e < 8; e++)
      if (e != i0 && lg[e] > v1) { v1 = lg[e]; i1 = e; }
    float ee = __expf(v1 - v0);
    float g0 = 1.0f / (1.0f + ee);
    float g1 = ee / (1.0f + ee);
    int4 rec;
    rec.x = i0; rec.y = i1;
    rec.z = __float_as_int(g0); rec.w = __float_as_int(g1);
    topk[t] = rec;
  }
}

// ---------------- Scatter: block-aggregated slot assignment -----------------
// 16 blocks x 512 threads, 1 token/thread. LDS-atomic local ranks, then ONE
// global atomicAdd per (block, expert): 128 global atomics total (was 16384).
__global__ __launch_bounds__(512) void scatter_kernel(
    const int4* __restrict__ topk, int* __restrict__ counts,
    int* __restrict__ tok, float* __restrict__ gat) {
  __shared__ int lcnt[NEXP], lbase[NEXP];
  const int tid = threadIdx.x;
  if (tid < NEXP) lcnt[tid] = 0;
  __syncthreads();
  const int t = blockIdx.x * 512 + tid;
  int4 r = topk[t];
  int s0 = atomicAdd(&lcnt[r.x], 1);
  int s1 = atomicAdd(&lcnt[r.y], 1);
  __syncthreads();
  if (tid < NEXP) lbase[tid] = atomicAdd(&counts[tid], lcnt[tid]);
  __syncthreads();
  int p0 = lbase[r.x] + s0;
  tok[r.x * CAP + p0] = t; gat[r.x * CAP + p0] = __int_as_float(r.z);
  int p1 = lbase[r.y] + s1;
  tok[r.y * CAP + p1] = t; gat[r.y * CAP + p1] = __int_as_float(r.w);
}

// ---------------- Routed expert GEMM + gated atomic combine -----------------
// Tile 128x128, BK=32, mfma_f32_16x16x32_bf16. 4 waves in 2x2, each 64x64.
// A rows gathered by token id (per-lane gptr into global_load_lds).
// LDS layout [row][32] bf16 (64B rows), chunk-XOR swizzle -> 2-way (free).
__global__ __launch_bounds__(256) void moe_gemm_kernel(
    const unsigned short* __restrict__ xbf, const unsigned short* __restrict__ wt,
    const float* __restrict__ bias, const int* __restrict__ counts,
    const int* __restrict__ tok, const float* __restrict__ gat,
    float* __restrict__ out) {
  const int e = blockIdx.z;
  const int cnt = counts[e];
  const int m0 = blockIdx.y * 128;
  if (m0 >= cnt) return;  // covers cnt==0
  const int n0 = blockIdx.x * 128;

  __shared__ __align__(16) unsigned short sA[128 * 32];
  __shared__ __align__(16) unsigned short sB[128 * 32];
  __shared__ int sTok[128];
  __shared__ float sGate[128];

  const int tid = threadIdx.x, wave = tid >> 6, lane = tid & 63;

  if (tid < 128) {
    int sr = m0 + tid;
    int cl = (sr < cnt) ? sr : (cnt - 1);
    sTok[tid] = tok[e * CAP + cl];
    sGate[tid] = gat[e * CAP + cl];
  }
  __syncthreads();

  // staging assignment: wave w stages 16-row groups {w, w+4} of A and B.
  // lane i -> row g*16 + (i>>2), chunk slot i&3; source chunk XOR-swizzled.
  const int rA1 = wave * 16 + (lane >> 2);
  const int rA2 = rA1 + 64;
  const int cch = lane & 3;
  const int cg1 = (cch ^ ((rA1 >> 1) & 3)) * 8;  // elements
  const int cg2 = (cch ^ ((rA2 >> 1) & 3)) * 8;
  const unsigned short* pA1 = xbf + (size_t)sTok[rA1] * DM + cg1;
  const unsigned short* pA2 = xbf + (size_t)sTok[rA2] * DM + cg2;
  const unsigned short* wte = wt + (size_t)e * DM * DM;
  const unsigned short* pB1 = wte + (size_t)(n0 + rA1) * DM + cg1;
  const unsigned short* pB2 = wte + (size_t)(n0 + rA2) * DM + cg2;
  unsigned short* lA1 = sA + wave * 512;        // 1024B per 16-row group
  unsigned short* lA2 = sA + (wave + 4) * 512;
  unsigned short* lB1 = sB + wave * 512;
  unsigned short* lB2 = sB + (wave + 4) * 512;

  // fragment read offsets (shorts): row*32 + swizzled 8-elem chunk
  const int q = lane >> 4, ml = lane & 15;
  const int wm = (wave >> 1) * 64, wn = (wave & 1) * 64;
  int offA[4], offB[4];
#pragma unroll
  for (int i = 0; i < 4; i++) {
    int row = wm + i * 16 + ml;
    offA[i] = row * 32 + (q ^ ((row >> 1) & 3)) * 8;
    int rowb = wn + i * 16 + ml;
    offB[i] = rowb * 32 + (q ^ ((rowb >> 1) & 3)) * 8;
  }

  f32x4 acc[4][4] = {};

  for (int k0 = 0; k0 < DM; k0 += 32) {
    gl_lds16(pA1 + k0, lA1);
    gl_lds16(pA2 + k0, lA2);
    gl_lds16(pB1 + k0, lB1);
    gl_lds16(pB2 + k0, lB2);
    __syncthreads();
    bf16x8 af[4], bf[4];
#pragma unroll
    for (int i = 0; i < 4; i++) af[i] = *(const bf16x8*)(sA + offA[i]);
#pragma unroll
    for (int i = 0; i < 4; i++) bf[i] = *(const bf16x8*)(sB + offB[i]);
#pragma unroll
    for (int mt = 0; mt < 4; mt++)
#pragma unroll
      for (int nt = 0; nt < 4; nt++)
        acc[mt][nt] = __builtin_amdgcn_mfma_f32_16x16x32_bf16(
            af[mt], bf[nt], acc[mt][nt], 0, 0, 0);
    __syncthreads();
  }

  // epilogue: out[t][col] += g * (acc + bias[e][col])  (exactly 2 adds/elem)
  const float* be = bias + (size_t)e * DM;
#pragma unroll
  for (int mt = 0; mt < 4; mt++) {
    int rbase = wm + mt * 16 + q * 4;
#pragma unroll
    for (int r = 0; r < 4; r++) {
      int row = rbase + r;
      if (m0 + row >= cnt) continue;
      int t = sTok[row];
      float g = sGate[row];
      float* orow = out + (size_t)t * DM + n0;
#pragma unroll
      for (int nt = 0; nt < 4; nt++) {
        int col = wn + nt * 16 + ml;
        atomicAdd(orow + col, g * (acc[mt][nt][r] + be[n0 + col]));
      }
    }
  }
}

extern "C" void kernel_launch(void* const* d_in, const int* in_sizes, int n_in,
                              void* d_out, int out_size, void* d_ws, size_t ws_size,
                              hipStream_t stream) {
  const float* x  = (const float*)d_in[0];
  const float* Wr = (const float*)d_in[1];
  const float* br = (const float*)d_in[2];
  const float* W  = (const float*)d_in[3];
  const float* b  = (const float*)d_in[4];
  float* out = (float*)d_out;

  // workspace layout (~32.7 MB)
  char* ws = (char*)d_ws;
  unsigned short* xbf = (unsigned short*)ws;                        // 16 MB
  unsigned short* wt  = (unsigned short*)(ws + (16u << 20));        // 16 MB
  int*   counts = (int*)(ws + (32u << 20));                         // 32 B
  int*   tok    = (int*)(ws + (32u << 20) + 4096);                  // 256 KB
  float* gat    = (float*)(ws + (32u << 20) + 4096 + (256u << 10)); // 256 KB
  int4*  topk   = (int4*)(ws + (32u << 20) + 4096 + (512u << 10));  // 128 KB

  hipMemsetAsync(d_out, 0, (size_t)out_size * sizeof(float), stream);
  hipMemsetAsync(counts, 0, NEXP * sizeof(int), stream);

  transpose_w_kernel<<<dim3(16, 16, 8), 256, 0, stream>>>(W, wt);
  router_compute_kernel<<<NTOK / 4, 256, 0, stream>>>(x, Wr, br, xbf, topk);
  scatter_kernel<<<16, 512, 0, stream>>>(topk, counts, tok, gat);
  moe_gemm_kernel<<<dim3(8, 64, 8), 256, 0, stream>>>(xbf, wt, b, counts, tok,
                                                      gat, out);
}